// Round 8
// baseline (215.327 us; speedup 1.0000x reference)
//
#include <hip/hip_runtime.h>
#include <hip/hip_bf16.h>

// CTC batch cost — split-phase, LINEAR-domain f64 recurrence.
// Phase 1: 4 waves fill LDS table lp[t][j] = (p[t][ext_j]+eps)*128 (f32).
// Phase 2: ONE wave per block runs the alpha recurrence in linear f64.
//   The recurrence wave index is derived from blockIdx so that co-resident
//   blocks place their serial wave on DIFFERENT SIMDs (wave w -> SIMD w%4),
//   instead of all stacking on SIMD 0.
// Final: loss = 256*ln(128) - ln(alpha[64]+alpha[63]).
// B=1024, T=256, C=128, L=32, S=65, blank=127.

#define CTC_B 1024
#define CTC_T 256
#define CTC_C 128
#define CTC_L 32
#define CTC_BLANK 127
#define CTC_EPS 1e-7f

#define RSTRIDE 33   // 32 labels + 1 blank per timestep

__global__ __launch_bounds__(256) void ctc_loss_kernel(
    const int* __restrict__ y_true,   // [B, L] int32
    const float* __restrict__ y_pred, // [B, T, C] float32
    float* __restrict__ out)          // [B, 1] float32
{
    __shared__ float lp[CTC_T * RSTRIDE];  // 33.8 KB -> 4 blocks/CU

    const int b = blockIdx.x;
    const int tid = threadIdx.x;
    const int lane = tid & 63;
    const int wave = tid >> 6;

    const float* yp = y_pred + (size_t)b * CTC_T * CTC_C;

    // per-lane gather label: lanes 0..31 -> y_true, lanes 32..63 -> blank
    int lbl = CTC_BLANK;
    if (lane < CTC_L) lbl = y_true[b * CTC_L + lane];

    // ---- phase 1: wave w handles t in [w*64, w*64+64) ----
    {
        const int t0 = wave * 64;
        #pragma unroll 8
        for (int k = 0; k < 64; ++k) {
            int t = t0 + k;
            float p = yp[t * CTC_C + lbl];
            float v = (p + CTC_EPS) * 128.0f;   // scaled linear prob
            if (lane <= 32) lp[t * RSTRIDE + lane] = v;
        }
    }
    __syncthreads();

    // spread the serial wave across SIMDs among co-resident blocks
    const int chain_wave = (b ^ (b >> 8)) & 3;
    if (wave != chain_wave) return;

    // ---- phase 2: lane i owns alpha[2i] (lo) and alpha[2i+1] (hi), f64 ----
    double skip = 0.0;
    if (lane >= 1 && lane < CTC_L) {
        int prev = y_true[b * CTC_L + lane - 1];
        if (prev != lbl) skip = 1.0;   // labels are never blank
    }
    const int lidx = (lane < 32) ? lane : 32;   // lanes>=32 read blank slot
    const bool alive = (lane < 32);             // lanes with a real odd state

    double lo = 0.0, hi = 0.0;
    if (lane == 0) {
        lo = (double)lp[32];   // alpha[0] = (p_blank+eps)*128 @ t=0
        hi = (double)lp[0];    // alpha[1] = (p_label0+eps)*128 @ t=0
    }

    // software-pipelined LDS reads (addresses independent of the chain)
    float lpv_f = lp[RSTRIDE + lidx];
    float lpb_f = lp[RSTRIDE + 32];

    for (int t = 1; t < CTC_T; ++t) {
        float lpv_n = 0.f, lpb_n = 0.f;
        if (t + 1 < CTC_T) {
            lpv_n = lp[(t + 1) * RSTRIDE + lidx];
            lpb_n = lp[(t + 1) * RSTRIDE + 32];
        }
        double pv = alive ? (double)lpv_f : 0.0;  // dead lanes: hi stays 0
        double pb = (double)lpb_f;

        // the only cross-lane op on the chain: alpha[2i-1] from lane i-1
        double ph = __shfl_up(hi, 1);
        if (lane == 0) ph = 0.0;

        // even state 2i (blank):   (alpha[2i] + alpha[2i-1]) * p_blank
        double nl = (lo + ph) * pb;
        // odd state 2i+1: (alpha[2i+1] + alpha[2i] + skip*alpha[2i-1]) * p_lbl
        double nh = (hi + lo + skip * ph) * pv;

        lo = nl; hi = nh;
        lpv_f = lpv_n; lpb_f = lpb_n;
    }

    // loss = 256*ln(128) - ln(alpha[64] + alpha[63])
    double aS1 = __shfl(lo, 32);   // alpha[64]
    double aS2 = __shfl(hi, 31);   // alpha[63]
    if (lane == 0) {
        out[b] = (float)(1242.1197475634219 - log(aS1 + aS2));
    }
}

extern "C" void kernel_launch(void* const* d_in, const int* in_sizes, int n_in,
                              void* d_out, int out_size, void* d_ws, size_t ws_size,
                              hipStream_t stream) {
    const int*   y_true = (const int*)d_in[0];
    const float* y_pred = (const float*)d_in[1];
    float*       out    = (float*)d_out;

    ctc_loss_kernel<<<CTC_B, 256, 0, stream>>>(y_true, y_pred, out);
}

// Round 9
// 214.394 us; speedup vs baseline: 1.0044x; 1.0044x over previous
//
#include <hip/hip_runtime.h>
#include <hip/hip_bf16.h>

// CTC batch cost — split-phase, LINEAR-domain f64 recurrence, 2 elements/wave.
// Phase 1: 4 waves fill pair-interleaved LDS table
//          lp[(t*33+j)*2 + e] = (p_e[t][ext_j]+eps)*128   (e = 0,1)
// Phase 2: one wave runs BOTH elements' alpha chains; the two independent
//          chains overlap each other's DS (shfl_up) and f64 ALU latency.
// Final: loss = 256*ln(128) - ln(alpha[64]+alpha[63]).
// B=1024, T=256, C=128, L=32, S=65, blank=127.

#define CTC_B 1024
#define CTC_T 256
#define CTC_C 128
#define CTC_L 32
#define CTC_BLANK 127
#define CTC_EPS 1e-7f

#define RSTRIDE 33   // 32 labels + 1 blank per timestep

__global__ __launch_bounds__(256) void ctc_loss_kernel(
    const int* __restrict__ y_true,   // [B, L] int32
    const float* __restrict__ y_pred, // [B, T, C] float32
    float* __restrict__ out)          // [B, 1] float32
{
    __shared__ float lp[CTC_T * RSTRIDE * 2];  // 67.6 KB -> 2 blocks/CU

    const int b0 = 2 * blockIdx.x;
    const int b1 = b0 + 1;
    const int tid = threadIdx.x;
    const int lane = tid & 63;
    const int wave = tid >> 6;

    const float* yp0 = y_pred + (size_t)b0 * CTC_T * CTC_C;
    const float* yp1 = y_pred + (size_t)b1 * CTC_T * CTC_C;

    // per-lane gather labels: lanes 0..31 -> y_true, lanes 32..63 -> blank
    int lbl0 = CTC_BLANK, lbl1 = CTC_BLANK;
    if (lane < CTC_L) {
        lbl0 = y_true[b0 * CTC_L + lane];
        lbl1 = y_true[b1 * CTC_L + lane];
    }

    // ---- phase 1: wave w handles t in [w*64, w*64+64) for BOTH elements ----
    {
        const int t0 = wave * 64;
        #pragma unroll 8
        for (int k = 0; k < 64; ++k) {
            int t = t0 + k;
            float p0 = yp0[t * CTC_C + lbl0];
            float p1 = yp1[t * CTC_C + lbl1];
            if (lane <= 32) {
                lp[(t * RSTRIDE + lane) * 2 + 0] = (p0 + CTC_EPS) * 128.0f;
                lp[(t * RSTRIDE + lane) * 2 + 1] = (p1 + CTC_EPS) * 128.0f;
            }
        }
    }
    __syncthreads();

    const int chain_wave = b0 & 3;   // spread chain waves across SIMDs
    if (wave != chain_wave) return;

    // ---- phase 2: lane i owns alpha[2i]/alpha[2i+1] for both elements ----
    double skip0 = 0.0, skip1 = 0.0;
    if (lane >= 1 && lane < CTC_L) {
        if (y_true[b0 * CTC_L + lane - 1] != lbl0) skip0 = 1.0;
        if (y_true[b1 * CTC_L + lane - 1] != lbl1) skip1 = 1.0;
    }
    const int lidx = (lane < 32) ? lane : 32;   // lanes>=32 read blank slot
    const bool alive = (lane < 32);             // lanes with a real odd state

    double lo0 = 0.0, hi0 = 0.0, lo1 = 0.0, hi1 = 0.0;
    if (lane == 0) {
        lo0 = (double)lp[32 * 2 + 0];  // alpha[0] = blank @ t=0
        hi0 = (double)lp[0 * 2 + 0];   // alpha[1] = label0 @ t=0
        lo1 = (double)lp[32 * 2 + 1];
        hi1 = (double)lp[0 * 2 + 1];
    }

    // software-pipelined LDS reads (addresses independent of the chain)
    float2 pvf = *(const float2*)&lp[(RSTRIDE + lidx) * 2];
    float2 pbf = *(const float2*)&lp[(RSTRIDE + 32) * 2];

    for (int t = 1; t < CTC_T; ++t) {
        float2 pvf_n = make_float2(0.f, 0.f), pbf_n = make_float2(0.f, 0.f);
        if (t + 1 < CTC_T) {
            pvf_n = *(const float2*)&lp[((t + 1) * RSTRIDE + lidx) * 2];
            pbf_n = *(const float2*)&lp[((t + 1) * RSTRIDE + 32) * 2];
        }
        double pv0 = alive ? (double)pvf.x : 0.0;
        double pv1 = alive ? (double)pvf.y : 0.0;
        double pb0 = (double)pbf.x;
        double pb1 = (double)pbf.y;

        // one DS round services both chains
        double ph0 = __shfl_up(hi0, 1);
        double ph1 = __shfl_up(hi1, 1);
        if (lane == 0) { ph0 = 0.0; ph1 = 0.0; }

        double nl0 = (lo0 + ph0) * pb0;
        double nh0 = (hi0 + lo0 + skip0 * ph0) * pv0;
        double nl1 = (lo1 + ph1) * pb1;
        double nh1 = (hi1 + lo1 + skip1 * ph1) * pv1;

        lo0 = nl0; hi0 = nh0; lo1 = nl1; hi1 = nh1;
        pvf = pvf_n; pbf = pbf_n;
    }

    // loss = 256*ln(128) - ln(alpha[64] + alpha[63])
    double aS1_0 = __shfl(lo0, 32), aS2_0 = __shfl(hi0, 31);
    double aS1_1 = __shfl(lo1, 32), aS2_1 = __shfl(hi1, 31);
    if (lane == 0) {
        out[b0] = (float)(1242.1197475634219 - log(aS1_0 + aS2_0));
        out[b1] = (float)(1242.1197475634219 - log(aS1_1 + aS2_1));
    }
}

extern "C" void kernel_launch(void* const* d_in, const int* in_sizes, int n_in,
                              void* d_out, int out_size, void* d_ws, size_t ws_size,
                              hipStream_t stream) {
    const int*   y_true = (const int*)d_in[0];
    const float* y_pred = (const float*)d_in[1];
    float*       out    = (float*)d_out;

    ctc_loss_kernel<<<CTC_B / 2, 256, 0, stream>>>(y_true, y_pred, out);
}

// Round 10
// 203.652 us; speedup vs baseline: 1.0573x; 1.0527x over previous
//
#include <hip/hip_runtime.h>
#include <hip/hip_bf16.h>

// CTC batch cost — split-phase, LINEAR-domain f64, FORWARD+BACKWARD meet in
// the middle: 128 sequential iterations instead of 255.
//   P = sum_s alpha_127[s] * beta_127[s]
// Forward: lane i holds alpha[2i] (lo), alpha[2i+1] (hi).
// Backward: lane i holds beta[2i+1] (a), beta[2i+2] (b); beta[0] in lane 32's a.
// All boundary masking baked into per-lane LDS table indices (slot 33 = 0)
// and bpermute address vectors — zero per-iteration masking instructions.
// B=1024, T=256, C=128, L=32, S=65, blank=127.

#define CTC_B 1024
#define CTC_T 256
#define CTC_C 128
#define CTC_L 32
#define CTC_BLANK 127
#define CTC_EPS 1e-7f

#define RSTRIDE 34   // 32 labels + blank(32) + zero slot(33)

__device__ __forceinline__ double bperm_f64(int addr, double v) {
    union { double d; int i[2]; } u; u.d = v;
    int x = __builtin_amdgcn_ds_bpermute(addr, u.i[0]);
    int y = __builtin_amdgcn_ds_bpermute(addr, u.i[1]);
    union { int i[2]; double d; } r; r.i[0] = x; r.i[1] = y;
    return r.d;
}

__global__ __launch_bounds__(256) void ctc_loss_kernel(
    const int* __restrict__ y_true,   // [B, L] int32
    const float* __restrict__ y_pred, // [B, T, C] float32
    float* __restrict__ out)          // [B, 1] float32
{
    __shared__ float lp[CTC_T * RSTRIDE];  // 34.8 KB -> 4 blocks/CU

    const int b = blockIdx.x;
    const int tid = threadIdx.x;
    const int lane = tid & 63;
    const int wave = tid >> 6;

    const float* yp = y_pred + (size_t)b * CTC_T * CTC_C;

    // per-lane gather label: lanes 0..31 -> y_true, others -> blank
    int lbl = CTC_BLANK;
    if (lane < CTC_L) lbl = y_true[b * CTC_L + lane];

    // ---- phase 1: wave w fills t in [w*64, w*64+64); slot 33 = 0 ----
    {
        const int t0 = wave * 64;
        #pragma unroll 8
        for (int k = 0; k < 64; ++k) {
            int t = t0 + k;
            float p = yp[t * CTC_C + lbl];
            float v = (lane == 33) ? 0.0f : (p + CTC_EPS) * 128.0f;
            if (lane <= 33) lp[t * RSTRIDE + lane] = v;
        }
    }
    __syncthreads();

    if (wave != 0) return;

    // ---- per-lane constants ----
    // forward skip: state 2i+1 may come from 2i-1 iff y[i] != y[i-1]
    double skip = 0.0;
    if (lane >= 1 && lane < CTC_L) {
        if (y_true[b * CTC_L + lane - 1] != lbl) skip = 1.0;
    }
    // backward skip-in: state 2i+3 reachable from 2i+1 iff y[i+1] != y[i]
    double skipn = 0.0;
    if (lane <= 30) {
        if (y_true[b * CTC_L + lane + 1] != lbl) skipn = 1.0;
    } else if (lane == 32) {
        skipn = 1.0;   // reuse v-term as the 0 -> 1 transition
    }

    const int lidx = (lane < 32) ? lane : 32;          // own label slot
    const int pv_idx = (lane < 32) ? lane : 33;        // fwd label (0 if dead)
    const int tn = (lane <= 30) ? (lane + 1)
                 : (lane == 31) ? 33                    // state 65: killed
                 : (lane == 32) ? 0                     // beta[0] uses p[1]
                 : 32;                                  // dead: harmless
    const int pbi = (lane == 32) ? 33 : 32;            // bwd blank (0 @ 32)

    const int fwd_addr = ((lane + 63) & 63) << 2;      // lane-1 (wrap: 0<-63)
    const int bwd_addr = (lane == 32) ? 0 : (((lane + 1) & 63) << 2);

    // ---- init ----
    double lo = 0.0, hi = 0.0;          // alpha
    if (lane == 0) {
        lo = (double)lp[32];            // alpha[0] = blank @ t=0
        hi = (double)lp[0];             // alpha[1] = label0 @ t=0
    }
    double a = 0.0, bb = 0.0;           // beta (a = odd 2i+1, bb = even 2i+2)
    if (lane == 31) { a = 1.0; bb = 1.0; }   // beta_255[63] = beta_255[64] = 1

    // ---- 127 interleaved iterations: fwd t=1..127, bwd t=255..129 ----
    for (int k = 0; k < 127; ++k) {
        const int tf = 1 + k;
        const int tb = 255 - k;
        float pvf  = lp[tf * RSTRIDE + pv_idx];
        float pbf  = lp[tf * RSTRIDE + 32];
        float paf  = lp[tb * RSTRIDE + lidx];
        float pa1f = lp[tb * RSTRIDE + tn];
        float pbbf = lp[tb * RSTRIDE + pbi];

        // one DS round: both chains' shuffles
        double ph = bperm_f64(fwd_addr, hi);   // alpha[2i-1]; lane0 <- 0
        double a1 = bperm_f64(bwd_addr, a);    // beta[2i+3]; lane32 <- beta[1]

        // forward
        double nl = (lo + ph) * (double)pbf;
        double nh = (hi + lo + skip * ph) * (double)pvf;
        // backward
        double v  = (double)pa1f * a1;
        double u  = (double)pbbf * bb;
        double nb = u + v;
        double na = fma((double)paf, a, fma(skipn, v, u));

        lo = nl; hi = nh; a = na; bb = nb;
    }

    // ---- final backward-only step: tb = 128 -> beta_127 ----
    {
        const int tb = 128;
        float paf  = lp[tb * RSTRIDE + lidx];
        float pa1f = lp[tb * RSTRIDE + tn];
        float pbbf = lp[tb * RSTRIDE + pbi];
        double a1 = bperm_f64(bwd_addr, a);
        double v  = (double)pa1f * a1;
        double u  = (double)pbbf * bb;
        double nb = u + v;
        double na = fma((double)paf, a, fma(skipn, v, u));
        a = na; bb = nb;
    }

    // ---- combine: P = sum_s alpha_127[s] * beta_127[s] ----
    // beta[2i]: i=0 -> a_32 (beta[0]); i>=1 -> bb_{i-1}
    double beA = bperm_f64(32 << 2, a);                      // all: a_32
    double beB = bperm_f64(((lane + 63) & 63) << 2, bb);     // bb_{i-1}
    double be = (lane == 0) ? beA : beB;
    double partial = (lane <= 32) ? (lo * be + hi * a) : 0.0;
    #pragma unroll
    for (int off = 32; off >= 1; off >>= 1)
        partial += __shfl_down(partial, off);
    if (lane == 0) {
        out[b] = (float)(1242.1197475634219 - log(partial)); // 256*ln(128)
    }
}

extern "C" void kernel_launch(void* const* d_in, const int* in_sizes, int n_in,
                              void* d_out, int out_size, void* d_ws, size_t ws_size,
                              hipStream_t stream) {
    const int*   y_true = (const int*)d_in[0];
    const float* y_pred = (const float*)d_in[1];
    float*       out    = (float*)d_out;

    ctc_loss_kernel<<<CTC_B, 256, 0, stream>>>(y_true, y_pred, out);
}